// Round 3
// baseline (286.727 us; speedup 1.0000x reference)
//
#include <hip/hip_runtime.h>
#include <hip/hip_bf16.h>

typedef unsigned short u16;
typedef unsigned char u8;
typedef short bf16x8 __attribute__((ext_vector_type(8)));
typedef float f32x4 __attribute__((ext_vector_type(4)));

__device__ __forceinline__ float bflo(unsigned u) { return __uint_as_float(u << 16); }
__device__ __forceinline__ float bfhi(unsigned u) { return __uint_as_float(u & 0xffff0000u); }
__device__ __forceinline__ u16 f2bf(float f) {
    unsigned u = __float_as_uint(f);
    return (u16)((u + 0x7fffu + ((u >> 16) & 1u)) >> 16);  // RNE
}

#define CHUNK 8192     // edges per block in pass A
#define BN 512         // nodes per bucket (bucket = c >> 9)

// binned entry packing: r in bits [0,23), (c & 511) in bits [23,32).
// Requires N <= 2^17 (N=100000) so r fits; bucket id recovered via LDS sideband.
#define PK_RMASK 0x7fffffu

// ---- pass A1: per-block bucket histogram (hist layout: [blk][bucket])
//      + fused W->bf16 transpose in trailing blocks ----
__global__ __launch_bounds__(256) void hist_prep_kernel(const int* __restrict__ cols,
                                                        unsigned* __restrict__ hist,
                                                        int E, int nbuckets, int nblocksA,
                                                        const float* __restrict__ W1,
                                                        const float* __restrict__ W2,
                                                        u16* __restrict__ WT1,
                                                        u16* __restrict__ WT2,
                                                        unsigned* __restrict__ done) {
    int blk = blockIdx.x;
    if (blk == 0 && threadIdx.x == 0) *done = 0u;   // reset fused-scan counter
    if (blk >= nblocksA) {
        int t = (blk - nblocksA) * 256 + threadIdx.x;
        if (t < 128 * 128) {
            int n = t >> 7, k = t & 127;
            WT1[n * 128 + k] = f2bf(W1[k * 128 + n]);
        } else if (t < 128 * 128 + 64 * 128) {
            int i = t - 128 * 128;
            int n = i >> 7, k = i & 127;
            WT2[n * 128 + k] = f2bf(W2[k * 64 + n]);
        }
        return;
    }
    __shared__ unsigned h[256];
    int t = threadIdx.x;
    h[t] = 0;
    __syncthreads();
    int base = blk * CHUNK;
#pragma unroll
    for (int j = 0; j < CHUNK / 256; j++) {
        int i = base + j * 256 + t;
        if (i < E) atomicAdd(&h[((unsigned)cols[i]) >> 9], 1u);
    }
    __syncthreads();
    if (t < nbuckets) hist[blk * nbuckets + t] = h[t];
}

// ---- fused pass A2: per-bucket prefix over blocks; last-done block also scans
//      bucket totals into bucketbase (saves one serial kernel launch).
//      Cross-XCD visibility: writers do __threadfence() before the done-count
//      atomic; the last block re-reads totals with atomicAdd(p,0) (device-
//      coherent read, bypasses stale L1). ----
__global__ __launch_bounds__(256) void scanA_fused(unsigned* __restrict__ hist,
                                                   unsigned* __restrict__ totals,
                                                   unsigned* __restrict__ bucketbase,
                                                   unsigned* __restrict__ done,
                                                   int nblocksA, int nbuckets) {
    __shared__ unsigned s[256];
    __shared__ unsigned rank;
    int t = threadIdx.x, b = blockIdx.x;
    unsigned val = (t < nblocksA) ? hist[t * nbuckets + b] : 0u;
    s[t] = val;
    __syncthreads();
    for (int off = 1; off < 256; off <<= 1) {
        unsigned v = (t >= off) ? s[t - off] : 0u;
        __syncthreads();
        s[t] += v;
        __syncthreads();
    }
    if (t < nblocksA) hist[t * nbuckets + b] = s[t] - val;  // exclusive
    if (t == 255) totals[b] = s[255];
    __threadfence();
    if (t == 0) rank = atomicAdd(done, 1u);
    __syncthreads();
    if (rank != (unsigned)(gridDim.x - 1)) return;

    // last block: scan totals -> bucketbase
    unsigned tv = (t < nbuckets) ? atomicAdd(&totals[t], 0u) : 0u;  // coherent read
    s[t] = tv;
    __syncthreads();
    for (int off = 1; off < 256; off <<= 1) {
        unsigned v = (t >= off) ? s[t - off] : 0u;
        __syncthreads();
        s[t] += v;
        __syncthreads();
    }
    unsigned ex = s[t] - tv;
    if (t < nbuckets) bucketbase[t] = ex;
    if (t == nbuckets - 1) bucketbase[nbuckets] = ex + tv;  // == E
}

// ---- pass A3: LDS-staged scatter -> coalesced bucket-group writes ----
// binned entries are packed u32 (halved traffic vs uint2); bucket id for the
// write phase is kept in a u8 sideband (nbuckets <= 256).
__global__ __launch_bounds__(256) void scatterA_kernel(const int* __restrict__ rows,
                                                       const int* __restrict__ cols,
                                                       const unsigned* __restrict__ hist,
                                                       const unsigned* __restrict__ bucketbase,
                                                       unsigned* __restrict__ binned,
                                                       int E, int nbuckets) {
    __shared__ unsigned sp[CHUNK];     // 32 KB staging (packed)
    __shared__ u8 spg[CHUNK];          // 8 KB bucket ids
    __shared__ unsigned lstart[256];   // LDS group starts
    __shared__ unsigned lcur[256];     // cursors
    __shared__ unsigned gbase[256];    // global base per bucket for this block
    int t = threadIdx.x, blk = blockIdx.x;
    int base = blk * CHUNK;
    int cnt = min(CHUNK, E - base);

    lcur[t] = 0;
    __syncthreads();
    for (int i = t; i < cnt; i += 256)
        atomicAdd(&lcur[((unsigned)cols[base + i]) >> 9], 1u);
    __syncthreads();
    unsigned val = lcur[t];
    lstart[t] = val;
    __syncthreads();
    for (int off = 1; off < 256; off <<= 1) {
        unsigned v = (t >= off) ? lstart[t - off] : 0u;
        __syncthreads();
        lstart[t] += v;
        __syncthreads();
    }
    unsigned ex = lstart[t] - val;
    __syncthreads();
    lstart[t] = ex;
    lcur[t] = ex;
    if (t < nbuckets) gbase[t] = bucketbase[t] + hist[blk * nbuckets + t];
    __syncthreads();
    for (int i = t; i < cnt; i += 256) {
        unsigned c = (unsigned)cols[base + i];
        unsigned r = (unsigned)rows[base + i];
        unsigned g = c >> 9;
        unsigned pos = atomicAdd(&lcur[g], 1u);
        sp[pos] = r | ((c & 511u) << 23);
        spg[pos] = (u8)g;
    }
    __syncthreads();
    for (int i = t; i < cnt; i += 256) {
        unsigned pk = sp[i];
        unsigned g = spg[i];
        binned[gbase[g] + (unsigned)i - lstart[g]] = pk;
    }
}

// ---- pass B: per bucket — local count/scan -> rowptr, dinv, srcidx ----
__global__ __launch_bounds__(256) void binB_kernel(const unsigned* __restrict__ binned,
                                                   const unsigned* __restrict__ bucketbase,
                                                   int* __restrict__ rowptr,
                                                   float* __restrict__ dinv,
                                                   int* __restrict__ srcidx,
                                                   int N, int E, int nbuckets) {
    __shared__ unsigned cnt[BN + 1];
    __shared__ unsigned sc[BN + 1];
    __shared__ unsigned ps[256];
    int t = threadIdx.x, b = blockIdx.x;
    int lo = b << 9;
    int nn = min(BN, N - lo);
    unsigned s = bucketbase[b], e = bucketbase[b + 1];

    cnt[t] = 0;
    cnt[t + 256] = 0;
    if (t == 0) cnt[BN] = 0;
    __syncthreads();
    for (unsigned i = s + t; i < e; i += 256)
        atomicAdd(&cnt[binned[i] >> 23], 1u);
    __syncthreads();

    unsigned a0 = cnt[2 * t], a1 = cnt[2 * t + 1];
    ps[t] = a0 + a1;
    __syncthreads();
    unsigned val = ps[t];
    for (int off = 1; off < 256; off <<= 1) {
        unsigned v = (t >= off) ? ps[t - off] : 0u;
        __syncthreads();
        ps[t] += v;
        __syncthreads();
    }
    unsigned ex = ps[t] - val;
    sc[2 * t] = ex;
    sc[2 * t + 1] = ex + a0;
    if (t == 255) sc[BN] = ex + val;
    __syncthreads();

    for (int n = t; n < nn; n += 256) {
        unsigned rp = s + sc[n];
        rowptr[lo + n] = (int)rp;
        dinv[lo + n] = rsqrtf((float)(sc[n + 1] - sc[n]) + 1.0f);
        cnt[n] = rp;
    }
    if (b == nbuckets - 1 && t == 0) rowptr[N] = E;
    __syncthreads();

    for (unsigned i = s + t; i < e; i += 256) {
        unsigned pk = binned[i];
        unsigned slot = atomicAdd(&cnt[pk >> 23], 1u);
        srcidx[slot] = (int)(pk & PK_RMASK);
    }
}

// ---- MFMA bf16 GEMM: OutH[i,:] = bf16((X[i,:] @ W) * dinv[i]) ----
template <int NOUT, bool IN_BF16>
__global__ __launch_bounds__(256) void gemm_mfma(const void* __restrict__ Xv,
                                                 const u16* __restrict__ WT,  // [NOUT][128] bf16
                                                 const float* __restrict__ dinv,
                                                 u16* __restrict__ OutH, int nrows) {
    constexpr int LDK = 136;
    __shared__ u16 sX[64 * LDK];
    __shared__ u16 sW[NOUT * LDK];

    const int t = threadIdx.x;
    const int wv = t >> 6, lane = t & 63;
    const int m = lane & 15, q = lane >> 4;
    const int row0 = blockIdx.x * 64;

    for (int idx = t; idx < NOUT * 16; idx += 256) {
        int n = idx >> 4, c = idx & 15;
        *((uint4*)&sW[n * LDK + c * 8]) = ((const uint4*)WT)[idx];
    }
    if (IN_BF16) {
        const u16* X = (const u16*)Xv;
        for (int idx = t; idx < 64 * 16; idx += 256) {
            int r = idx >> 4, c = idx & 15;
            int gr = row0 + r;
            uint4 v = make_uint4(0u, 0u, 0u, 0u);
            if (gr < nrows) v = ((const uint4*)X)[(size_t)gr * 16 + c];
            *((uint4*)&sX[r * LDK + c * 8]) = v;
        }
    } else {
        const float* X = (const float*)Xv;
        for (int idx = t; idx < 64 * 32; idx += 256) {
            int r = idx >> 5, c = idx & 31;
            int gr = row0 + r;
            float4 v = make_float4(0.f, 0.f, 0.f, 0.f);
            if (gr < nrows) v = ((const float4*)X)[(size_t)gr * 32 + c];
            uint2 o;
            o.x = (unsigned)f2bf(v.x) | ((unsigned)f2bf(v.y) << 16);
            o.y = (unsigned)f2bf(v.z) | ((unsigned)f2bf(v.w) << 16);
            *((uint2*)&sX[r * LDK + c * 4]) = o;
        }
    }
    __syncthreads();

    f32x4 acc[NOUT / 16];
#pragma unroll
    for (int i = 0; i < NOUT / 16; i++) acc[i] = (f32x4){0.f, 0.f, 0.f, 0.f};

#pragma unroll
    for (int ks = 0; ks < 4; ks++) {
        const int k0 = ks * 32 + q * 8;
        bf16x8 a = *((const bf16x8*)&sX[(wv * 16 + m) * LDK + k0]);
#pragma unroll
        for (int nt = 0; nt < NOUT / 16; nt++) {
            bf16x8 b = *((const bf16x8*)&sW[(nt * 16 + m) * LDK + k0]);
            acc[nt] = __builtin_amdgcn_mfma_f32_16x16x32_bf16(a, b, acc[nt], 0, 0, 0);
        }
    }

#pragma unroll
    for (int r = 0; r < 4; r++) {
        int gi = row0 + wv * 16 + q * 4 + r;
        if (gi < nrows) {
            float dv = dinv[gi];
#pragma unroll
            for (int nt = 0; nt < NOUT / 16; nt++) {
                OutH[(size_t)gi * NOUT + nt * 16 + m] = f2bf(acc[nt][r] * dv);
            }
        }
    }
}

// ---- fused layer-1 aggregate + relu + layer-2 GEMM ----
// 256 threads = 16 nodes per block (round-0 proven shape; 512-thr regressed:
// 8-wave barrier couples to slowest node + 4-block cap). W2^T is NOT staged in
// LDS: it's one hot 16 KB block, L1/L2-resident — phase 2 reads B-fragments
// straight from global after the barrier. LDS = sO only (4352 B) -> 8 blocks/CU
// x 4 waves = 32 waves = 100% theoretical occupancy (vs 7 blocks = 87.5%).
__global__ __launch_bounds__(256) void agg1_gemm2(const int* __restrict__ rowptr,
                                                  const int* __restrict__ srcidx,
                                                  const u16* __restrict__ hs,     // h1s [N][128] bf16
                                                  const float* __restrict__ dinv,
                                                  const float* __restrict__ bias, // b1
                                                  const u16* __restrict__ WT2,    // [64][128] bf16
                                                  u16* __restrict__ h2s, int N) {
    constexpr int WPN = 16;   // lanes per node (128 feats / 8 per lane)
    constexpr int LDK = 136;
    __shared__ u16 sO[16 * LDK];

    const int t = threadIdx.x;
    const int node_l = t / WPN;         // 0..15
    const int fl = t % WPN;
    const int node = blockIdx.x * 16 + node_l;
    const bool valid = node < N;

    // ---- phase 1: aggregation ----
    const uint4* h128 = (const uint4*)hs;
    float a[8];
#pragma unroll
    for (int j = 0; j < 8; j++) a[j] = 0.f;

    if (valid) {
        int start = rowptr[node], end = rowptr[node + 1];
        {
            uint4 v = h128[(size_t)node * WPN + fl];  // self loop
            a[0] = bflo(v.x); a[1] = bfhi(v.x); a[2] = bflo(v.y); a[3] = bfhi(v.y);
            a[4] = bflo(v.z); a[5] = bfhi(v.z); a[6] = bflo(v.w); a[7] = bfhi(v.w);
        }
        int nfull = (end - start) >> 3;
        int i = start;
        int r[8], r2[8];
        if (nfull > 0) {
#pragma unroll
            for (int j = 0; j < 8; j++) r[j] = srcidx[i + j];
        }
        for (int b = 0; b < nfull; b++) {
            uint4 u[8];
#pragma unroll
            for (int j = 0; j < 8; j++) u[j] = h128[(size_t)r[j] * WPN + fl];
            if (b + 1 < nfull) {
#pragma unroll
                for (int j = 0; j < 8; j++) r2[j] = srcidx[i + 8 + j];
            }
#pragma unroll
            for (int j = 0; j < 8; j++) {
                a[0] += bflo(u[j].x); a[1] += bfhi(u[j].x);
                a[2] += bflo(u[j].y); a[3] += bfhi(u[j].y);
                a[4] += bflo(u[j].z); a[5] += bfhi(u[j].z);
                a[6] += bflo(u[j].w); a[7] += bfhi(u[j].w);
            }
#pragma unroll
            for (int j = 0; j < 8; j++) r[j] = r2[j];
            i += 8;
        }
        if (i + 4 <= end) {
            int rr[4];
#pragma unroll
            for (int j = 0; j < 4; j++) rr[j] = srcidx[i + j];
            uint4 u[4];
#pragma unroll
            for (int j = 0; j < 4; j++) u[j] = h128[(size_t)rr[j] * WPN + fl];
#pragma unroll
            for (int j = 0; j < 4; j++) {
                a[0] += bflo(u[j].x); a[1] += bfhi(u[j].x);
                a[2] += bflo(u[j].y); a[3] += bfhi(u[j].y);
                a[4] += bflo(u[j].z); a[5] += bfhi(u[j].z);
                a[6] += bflo(u[j].w); a[7] += bfhi(u[j].w);
            }
            i += 4;
        }
        for (; i < end; ++i) {
            uint4 u = h128[(size_t)srcidx[i] * WPN + fl];
            a[0] += bflo(u.x); a[1] += bfhi(u.x);
            a[2] += bflo(u.y); a[3] += bfhi(u.y);
            a[4] += bflo(u.z); a[5] += bfhi(u.z);
            a[6] += bflo(u.w); a[7] += bfhi(u.w);
        }
    }

    float dv = valid ? dinv[node] : 0.f;
    float4 bv0 = ((const float4*)bias)[2 * fl];
    float4 bv1 = ((const float4*)bias)[2 * fl + 1];
    float o[8];
    o[0] = fmaxf(dv * a[0] + bv0.x, 0.f); o[1] = fmaxf(dv * a[1] + bv0.y, 0.f);
    o[2] = fmaxf(dv * a[2] + bv0.z, 0.f); o[3] = fmaxf(dv * a[3] + bv0.w, 0.f);
    o[4] = fmaxf(dv * a[4] + bv1.x, 0.f); o[5] = fmaxf(dv * a[5] + bv1.y, 0.f);
    o[6] = fmaxf(dv * a[6] + bv1.z, 0.f); o[7] = fmaxf(dv * a[7] + bv1.w, 0.f);
    uint4 w;
    w.x = (unsigned)f2bf(o[0]) | ((unsigned)f2bf(o[1]) << 16);
    w.y = (unsigned)f2bf(o[2]) | ((unsigned)f2bf(o[3]) << 16);
    w.z = (unsigned)f2bf(o[4]) | ((unsigned)f2bf(o[5]) << 16);
    w.w = (unsigned)f2bf(o[6]) | ((unsigned)f2bf(o[7]) << 16);
    *((uint4*)&sO[node_l * LDK + fl * 8]) = w;
    __syncthreads();

    // ---- phase 2: 16x64 GEMM vs W2 (wave wv -> feature tile wv*16);
    //      B-fragments read directly from global WT2 (L1/L2-hot 16 KB) ----
    const int wv = t >> 6, lane = t & 63;
    const int m = lane & 15, q = lane >> 4;
    f32x4 acc = (f32x4){0.f, 0.f, 0.f, 0.f};
#pragma unroll
    for (int ks = 0; ks < 4; ks++) {
        const int k0 = ks * 32 + q * 8;
        bf16x8 af = *((const bf16x8*)&sO[m * LDK + k0]);
        bf16x8 bf = *((const bf16x8*)&WT2[(wv * 16 + m) * 128 + k0]);
        acc = __builtin_amdgcn_mfma_f32_16x16x32_bf16(af, bf, acc, 0, 0, 0);
    }
#pragma unroll
    for (int r = 0; r < 4; r++) {
        int gi = blockIdx.x * 16 + q * 4 + r;
        if (gi < N) {
            float dvv = dinv[gi];
            h2s[(size_t)gi * 64 + wv * 16 + m] = f2bf(acc[r] * dvv);
        }
    }
}

// ---- aggregate+finalize (layer 2): out[c] = dinv[c]*(Σ h2s[r] + h2s[c]) + b2 ----
template <int NH, bool RELU, bool OUT_BF16>
__global__ __launch_bounds__(256) void aggregate(const int* __restrict__ rowptr,
                                                 const int* __restrict__ srcidx,
                                                 const u16* __restrict__ hs,
                                                 const float* __restrict__ dinv,
                                                 const float* __restrict__ bias,
                                                 void* __restrict__ outv, int N) {
    constexpr int WPN = NH / 8;
    int tid = blockIdx.x * 256 + threadIdx.x;
    int node = tid / WPN;
    int fl = tid % WPN;
    if (node >= N) return;

    const uint4* h128 = (const uint4*)hs;
    int start = rowptr[node], end = rowptr[node + 1];

    float a[8];
    {
        uint4 v = h128[(size_t)node * WPN + fl];
        a[0] = bflo(v.x); a[1] = bfhi(v.x); a[2] = bflo(v.y); a[3] = bfhi(v.y);
        a[4] = bflo(v.z); a[5] = bfhi(v.z); a[6] = bflo(v.w); a[7] = bfhi(v.w);
    }

    int nfull = (end - start) >> 3;
    int i = start;
    int r[8], r2[8];
    if (nfull > 0) {
#pragma unroll
        for (int j = 0; j < 8; j++) r[j] = srcidx[i + j];
    }
    for (int b = 0; b < nfull; b++) {
        uint4 u[8];
#pragma unroll
        for (int j = 0; j < 8; j++) u[j] = h128[(size_t)r[j] * WPN + fl];
        if (b + 1 < nfull) {
#pragma unroll
            for (int j = 0; j < 8; j++) r2[j] = srcidx[i + 8 + j];
        }
#pragma unroll
        for (int j = 0; j < 8; j++) {
            a[0] += bflo(u[j].x); a[1] += bfhi(u[j].x);
            a[2] += bflo(u[j].y); a[3] += bfhi(u[j].y);
            a[4] += bflo(u[j].z); a[5] += bfhi(u[j].z);
            a[6] += bflo(u[j].w); a[7] += bfhi(u[j].w);
        }
#pragma unroll
        for (int j = 0; j < 8; j++) r[j] = r2[j];
        i += 8;
    }
    if (i + 4 <= end) {
        int rr[4];
#pragma unroll
        for (int j = 0; j < 4; j++) rr[j] = srcidx[i + j];
        uint4 u[4];
#pragma unroll
        for (int j = 0; j < 4; j++) u[j] = h128[(size_t)rr[j] * WPN + fl];
#pragma unroll
        for (int j = 0; j < 4; j++) {
            a[0] += bflo(u[j].x); a[1] += bfhi(u[j].x);
            a[2] += bflo(u[j].y); a[3] += bfhi(u[j].y);
            a[4] += bflo(u[j].z); a[5] += bfhi(u[j].z);
            a[6] += bflo(u[j].w); a[7] += bfhi(u[j].w);
        }
        i += 4;
    }
    for (; i < end; ++i) {
        uint4 u = h128[(size_t)srcidx[i] * WPN + fl];
        a[0] += bflo(u.x); a[1] += bfhi(u.x);
        a[2] += bflo(u.y); a[3] += bfhi(u.y);
        a[4] += bflo(u.z); a[5] += bfhi(u.z);
        a[6] += bflo(u.w); a[7] += bfhi(u.w);
    }

    float dv = dinv[node];
    float4 bv0 = ((const float4*)bias)[2 * fl];
    float4 bv1 = ((const float4*)bias)[2 * fl + 1];
    float o[8];
    o[0] = dv * a[0] + bv0.x; o[1] = dv * a[1] + bv0.y;
    o[2] = dv * a[2] + bv0.z; o[3] = dv * a[3] + bv0.w;
    o[4] = dv * a[4] + bv1.x; o[5] = dv * a[5] + bv1.y;
    o[6] = dv * a[6] + bv1.z; o[7] = dv * a[7] + bv1.w;
    if (RELU) {
#pragma unroll
        for (int j = 0; j < 8; j++) o[j] = fmaxf(o[j], 0.f);
    }
    if (OUT_BF16) {
        uint4 w;
        w.x = (unsigned)f2bf(o[0]) | ((unsigned)f2bf(o[1]) << 16);
        w.y = (unsigned)f2bf(o[2]) | ((unsigned)f2bf(o[3]) << 16);
        w.z = (unsigned)f2bf(o[4]) | ((unsigned)f2bf(o[5]) << 16);
        w.w = (unsigned)f2bf(o[6]) | ((unsigned)f2bf(o[7]) << 16);
        ((uint4*)outv)[tid] = w;
    } else {
        ((float4*)outv)[2 * tid] = make_float4(o[0], o[1], o[2], o[3]);
        ((float4*)outv)[2 * tid + 1] = make_float4(o[4], o[5], o[6], o[7]);
    }
}

extern "C" void kernel_launch(void* const* d_in, const int* in_sizes, int n_in,
                              void* d_out, int out_size, void* d_ws, size_t ws_size,
                              hipStream_t stream) {
    const float* x  = (const float*)d_in[0];
    const int*   ei = (const int*)d_in[1];
    const float* W1 = (const float*)d_in[2];
    const float* b1 = (const float*)d_in[3];
    const float* W2 = (const float*)d_in[4];
    const float* b2 = (const float*)d_in[5];

    const int N = in_sizes[0] / 128;
    const int E = in_sizes[1] / 2;
    const int* rows = ei;
    const int* cols = ei + E;

    const int nbuckets = (N + BN - 1) / BN;          // 196 for N=100k (<=256)
    const int nblocksA = (E + CHUNK - 1) / CHUNK;    // 196 for E=1.6M (<=256)

    char* ws = (char*)d_ws;
    size_t off = 0;
    auto alloc = [&](size_t bytes) -> void* {
        void* p = ws + off;
        off = (off + bytes + 1023) & ~(size_t)1023;
        return p;
    };
    unsigned* hist       = (unsigned*)alloc((size_t)nbuckets * nblocksA * 4);
    unsigned* totals     = (unsigned*)alloc(256 * 4);
    unsigned* bucketbase = (unsigned*)alloc((size_t)(nbuckets + 1) * 4);
    unsigned* done       = (unsigned*)alloc(4);
    unsigned* binned     = (unsigned*)alloc((size_t)E * 4);
    int*      rowptr     = (int*)alloc((size_t)(N + 1) * 4);
    float*    dinv       = (float*)alloc((size_t)N * 4);
    int*      srcidx     = (int*)alloc((size_t)E * 4);
    u16*      WT1        = (u16*)alloc((size_t)128 * 128 * 2);
    u16*      WT2        = (u16*)alloc((size_t)64 * 128 * 2);
    u16*      h1s        = (u16*)alloc((size_t)N * 128 * 2);
    u16*      h2s        = (u16*)alloc((size_t)N * 64 * 2);

    // CSR build (binned two-level counting sort) + fused weight prep
    hist_prep_kernel<<<nblocksA + 96, 256, 0, stream>>>(cols, hist, E, nbuckets, nblocksA,
                                                        W1, W2, WT1, WT2, done);
    scanA_fused<<<nbuckets, 256, 0, stream>>>(hist, totals, bucketbase, done, nblocksA, nbuckets);
    scatterA_kernel<<<nblocksA, 256, 0, stream>>>(rows, cols, hist, bucketbase, binned, E, nbuckets);
    binB_kernel<<<nbuckets, 256, 0, stream>>>(binned, bucketbase, rowptr, dinv, srcidx, N, E, nbuckets);

    // layer 1 GEMM
    gemm_mfma<128, false><<<(N + 63) / 64, 256, 0, stream>>>(x, WT1, dinv, h1s, N);

    // fused: layer-1 aggregate + relu + layer-2 GEMM (256 thr, 16 nodes/blk)
    agg1_gemm2<<<(N + 15) / 16, 256, 0, stream>>>(rowptr, srcidx, h1s, dinv, b1, WT2, h2s, N);

    // layer-2 aggregate + bias -> fp32 out
    aggregate<64, false, false><<<(N * 8 + 255) / 256, 256, 0, stream>>>(
        rowptr, srcidx, h2s, dinv, b2, d_out, N);
}

// Round 4
// 284.678 us; speedup vs baseline: 1.0072x; 1.0072x over previous
//
#include <hip/hip_runtime.h>
#include <hip/hip_bf16.h>

typedef unsigned short u16;
typedef unsigned char u8;
typedef short bf16x8 __attribute__((ext_vector_type(8)));
typedef float f32x4 __attribute__((ext_vector_type(4)));

__device__ __forceinline__ float bflo(unsigned u) { return __uint_as_float(u << 16); }
__device__ __forceinline__ float bfhi(unsigned u) { return __uint_as_float(u & 0xffff0000u); }
__device__ __forceinline__ u16 f2bf(float f) {
    unsigned u = __float_as_uint(f);
    return (u16)((u + 0x7fffu + ((u >> 16) & 1u)) >> 16);  // RNE
}

#define CHUNK 8192     // edges per block in pass A
#define BN 512         // nodes per bucket (bucket = c >> 9)

// binned entry packing: r in bits [0,23), (c & 511) in bits [23,32).
// Requires N <= 2^17 (N=100000) so r fits; bucket id recovered via LDS sideband.
#define PK_RMASK 0x7fffffu

// ---- pass A1: per-block bucket histogram (hist layout: [blk][bucket])
//      + fused W->bf16 transpose in trailing blocks ----
__global__ __launch_bounds__(256) void hist_prep_kernel(const int* __restrict__ cols,
                                                        unsigned* __restrict__ hist,
                                                        int E, int nbuckets, int nblocksA,
                                                        const float* __restrict__ W1,
                                                        const float* __restrict__ W2,
                                                        u16* __restrict__ WT1,
                                                        u16* __restrict__ WT2) {
    int blk = blockIdx.x;
    if (blk >= nblocksA) {
        int t = (blk - nblocksA) * 256 + threadIdx.x;
        if (t < 128 * 128) {
            int n = t >> 7, k = t & 127;
            WT1[n * 128 + k] = f2bf(W1[k * 128 + n]);
        } else if (t < 128 * 128 + 64 * 128) {
            int i = t - 128 * 128;
            int n = i >> 7, k = i & 127;
            WT2[n * 128 + k] = f2bf(W2[k * 64 + n]);
        }
        return;
    }
    __shared__ unsigned h[256];
    int t = threadIdx.x;
    h[t] = 0;
    __syncthreads();
    int base = blk * CHUNK;
#pragma unroll
    for (int j = 0; j < CHUNK / 256; j++) {
        int i = base + j * 256 + t;
        if (i < E) atomicAdd(&h[((unsigned)cols[i]) >> 9], 1u);
    }
    __syncthreads();
    if (t < nbuckets) hist[blk * nbuckets + t] = h[t];
}

// ---- pass A2a: per-bucket prefix over blocks (one WG per bucket) ----
__global__ __launch_bounds__(256) void scanA1_kernel(unsigned* __restrict__ hist,
                                                     unsigned* __restrict__ totals,
                                                     int nblocksA, int nbuckets) {
    __shared__ unsigned s[256];
    int t = threadIdx.x, b = blockIdx.x;
    unsigned val = (t < nblocksA) ? hist[t * nbuckets + b] : 0u;
    s[t] = val;
    __syncthreads();
    for (int off = 1; off < 256; off <<= 1) {
        unsigned v = (t >= off) ? s[t - off] : 0u;
        __syncthreads();
        s[t] += v;
        __syncthreads();
    }
    if (t < nblocksA) hist[t * nbuckets + b] = s[t] - val;  // exclusive
    if (t == 255) totals[b] = s[255];
}

// ---- pass A2b: bucket bases (single WG) ----
__global__ __launch_bounds__(256) void scanA2_kernel(const unsigned* __restrict__ totals,
                                                     unsigned* __restrict__ bucketbase,
                                                     int nbuckets) {
    __shared__ unsigned s[256];
    int t = threadIdx.x;
    unsigned val = (t < nbuckets) ? totals[t] : 0u;
    s[t] = val;
    __syncthreads();
    for (int off = 1; off < 256; off <<= 1) {
        unsigned v = (t >= off) ? s[t - off] : 0u;
        __syncthreads();
        s[t] += v;
        __syncthreads();
    }
    unsigned ex = s[t] - val;
    if (t < nbuckets) bucketbase[t] = ex;
    if (t == nbuckets - 1) bucketbase[nbuckets] = ex + val;  // == E
}

// ---- pass A3: LDS-staged scatter -> coalesced bucket-group writes ----
// binned entries are packed u32 (halved traffic vs uint2); bucket id for the
// write phase is kept in a u8 sideband (nbuckets <= 256).
__global__ __launch_bounds__(256) void scatterA_kernel(const int* __restrict__ rows,
                                                       const int* __restrict__ cols,
                                                       const unsigned* __restrict__ hist,
                                                       const unsigned* __restrict__ bucketbase,
                                                       unsigned* __restrict__ binned,
                                                       int E, int nbuckets) {
    __shared__ unsigned sp[CHUNK];     // 32 KB staging (packed)
    __shared__ u8 spg[CHUNK];          // 8 KB bucket ids
    __shared__ unsigned lstart[256];   // LDS group starts
    __shared__ unsigned lcur[256];     // cursors
    __shared__ unsigned gbase[256];    // global base per bucket for this block
    int t = threadIdx.x, blk = blockIdx.x;
    int base = blk * CHUNK;
    int cnt = min(CHUNK, E - base);

    lcur[t] = 0;
    __syncthreads();
    for (int i = t; i < cnt; i += 256)
        atomicAdd(&lcur[((unsigned)cols[base + i]) >> 9], 1u);
    __syncthreads();
    unsigned val = lcur[t];
    lstart[t] = val;
    __syncthreads();
    for (int off = 1; off < 256; off <<= 1) {
        unsigned v = (t >= off) ? lstart[t - off] : 0u;
        __syncthreads();
        lstart[t] += v;
        __syncthreads();
    }
    unsigned ex = lstart[t] - val;
    __syncthreads();
    lstart[t] = ex;
    lcur[t] = ex;
    if (t < nbuckets) gbase[t] = bucketbase[t] + hist[blk * nbuckets + t];
    __syncthreads();
    for (int i = t; i < cnt; i += 256) {
        unsigned c = (unsigned)cols[base + i];
        unsigned r = (unsigned)rows[base + i];
        unsigned g = c >> 9;
        unsigned pos = atomicAdd(&lcur[g], 1u);
        sp[pos] = r | ((c & 511u) << 23);
        spg[pos] = (u8)g;
    }
    __syncthreads();
    for (int i = t; i < cnt; i += 256) {
        unsigned pk = sp[i];
        unsigned g = spg[i];
        binned[gbase[g] + (unsigned)i - lstart[g]] = pk;
    }
}

// ---- pass B: per bucket — local count/scan -> rowptr, dinv, srcidx,
//      plus in-bucket degree-sort -> perm (uniform-degree blocks for the
//      gather kernels; removes wave/barrier tail imbalance). perm is a true
//      permutation of [0,N); agg kernels process nodes in perm order and
//      scatter outputs to original ids (per-node sum order unchanged). ----
__global__ __launch_bounds__(256) void binB_kernel(const unsigned* __restrict__ binned,
                                                   const unsigned* __restrict__ bucketbase,
                                                   int* __restrict__ rowptr,
                                                   float* __restrict__ dinv,
                                                   int* __restrict__ srcidx,
                                                   int* __restrict__ perm,
                                                   int N, int E, int nbuckets) {
    __shared__ unsigned cnt[BN + 1];
    __shared__ unsigned sc[BN + 1];
    __shared__ unsigned ps[256];
    __shared__ unsigned dh[64];
    __shared__ unsigned dcur[64];
    int t = threadIdx.x, b = blockIdx.x;
    int lo = b << 9;
    int nn = min(BN, N - lo);
    unsigned s = bucketbase[b], e = bucketbase[b + 1];

    cnt[t] = 0;
    cnt[t + 256] = 0;
    if (t == 0) cnt[BN] = 0;
    __syncthreads();
    for (unsigned i = s + t; i < e; i += 256)
        atomicAdd(&cnt[binned[i] >> 23], 1u);
    __syncthreads();

    unsigned a0 = cnt[2 * t], a1 = cnt[2 * t + 1];
    ps[t] = a0 + a1;
    __syncthreads();
    unsigned val = ps[t];
    for (int off = 1; off < 256; off <<= 1) {
        unsigned v = (t >= off) ? ps[t - off] : 0u;
        __syncthreads();
        ps[t] += v;
        __syncthreads();
    }
    unsigned ex = ps[t] - val;
    sc[2 * t] = ex;
    sc[2 * t + 1] = ex + a0;
    if (t == 255) sc[BN] = ex + val;
    __syncthreads();

    for (int n = t; n < nn; n += 256) {
        unsigned rp = s + sc[n];
        rowptr[lo + n] = (int)rp;
        dinv[lo + n] = rsqrtf((float)(sc[n + 1] - sc[n]) + 1.0f);
        cnt[n] = rp;
    }
    if (b == nbuckets - 1 && t == 0) rowptr[N] = E;
    __syncthreads();

    // ---- in-bucket counting sort of nodes by degree (clamped at 63) ----
    if (t < 64) dh[t] = 0;
    __syncthreads();
    for (int n = t; n < nn; n += 256) {
        unsigned d = min(sc[n + 1] - sc[n], 63u);
        atomicAdd(&dh[d], 1u);
    }
    __syncthreads();
    if (t == 0) {
        unsigned acc = 0;
        for (int d = 0; d < 64; d++) { unsigned c = dh[d]; dh[d] = acc; acc += c; }
    }
    __syncthreads();
    if (t < 64) dcur[t] = dh[t];
    __syncthreads();
    for (int n = t; n < nn; n += 256) {
        unsigned d = min(sc[n + 1] - sc[n], 63u);
        unsigned p = atomicAdd(&dcur[d], 1u);
        perm[lo + (int)p] = lo + n;
    }

    for (unsigned i = s + t; i < e; i += 256) {
        unsigned pk = binned[i];
        unsigned slot = atomicAdd(&cnt[pk >> 23], 1u);
        srcidx[slot] = (int)(pk & PK_RMASK);
    }
}

// ---- MFMA bf16 GEMM: OutH[i,:] = bf16((X[i,:] @ W) * dinv[i]) ----
template <int NOUT, bool IN_BF16>
__global__ __launch_bounds__(256) void gemm_mfma(const void* __restrict__ Xv,
                                                 const u16* __restrict__ WT,  // [NOUT][128] bf16
                                                 const float* __restrict__ dinv,
                                                 u16* __restrict__ OutH, int nrows) {
    constexpr int LDK = 136;
    __shared__ u16 sX[64 * LDK];
    __shared__ u16 sW[NOUT * LDK];

    const int t = threadIdx.x;
    const int wv = t >> 6, lane = t & 63;
    const int m = lane & 15, q = lane >> 4;
    const int row0 = blockIdx.x * 64;

    for (int idx = t; idx < NOUT * 16; idx += 256) {
        int n = idx >> 4, c = idx & 15;
        *((uint4*)&sW[n * LDK + c * 8]) = ((const uint4*)WT)[idx];
    }
    if (IN_BF16) {
        const u16* X = (const u16*)Xv;
        for (int idx = t; idx < 64 * 16; idx += 256) {
            int r = idx >> 4, c = idx & 15;
            int gr = row0 + r;
            uint4 v = make_uint4(0u, 0u, 0u, 0u);
            if (gr < nrows) v = ((const uint4*)X)[(size_t)gr * 16 + c];
            *((uint4*)&sX[r * LDK + c * 8]) = v;
        }
    } else {
        const float* X = (const float*)Xv;
        for (int idx = t; idx < 64 * 32; idx += 256) {
            int r = idx >> 5, c = idx & 31;
            int gr = row0 + r;
            float4 v = make_float4(0.f, 0.f, 0.f, 0.f);
            if (gr < nrows) v = ((const float4*)X)[(size_t)gr * 32 + c];
            uint2 o;
            o.x = (unsigned)f2bf(v.x) | ((unsigned)f2bf(v.y) << 16);
            o.y = (unsigned)f2bf(v.z) | ((unsigned)f2bf(v.w) << 16);
            *((uint2*)&sX[r * LDK + c * 4]) = o;
        }
    }
    __syncthreads();

    f32x4 acc[NOUT / 16];
#pragma unroll
    for (int i = 0; i < NOUT / 16; i++) acc[i] = (f32x4){0.f, 0.f, 0.f, 0.f};

#pragma unroll
    for (int ks = 0; ks < 4; ks++) {
        const int k0 = ks * 32 + q * 8;
        bf16x8 a = *((const bf16x8*)&sX[(wv * 16 + m) * LDK + k0]);
#pragma unroll
        for (int nt = 0; nt < NOUT / 16; nt++) {
            bf16x8 b = *((const bf16x8*)&sW[(nt * 16 + m) * LDK + k0]);
            acc[nt] = __builtin_amdgcn_mfma_f32_16x16x32_bf16(a, b, acc[nt], 0, 0, 0);
        }
    }

#pragma unroll
    for (int r = 0; r < 4; r++) {
        int gi = row0 + wv * 16 + q * 4 + r;
        if (gi < nrows) {
            float dv = dinv[gi];
#pragma unroll
            for (int nt = 0; nt < NOUT / 16; nt++) {
                OutH[(size_t)gi * NOUT + nt * 16 + m] = f2bf(acc[nt][r] * dv);
            }
        }
    }
}

// ---- fused layer-1 aggregate + relu + layer-2 GEMM ----
// Round-0 proven shape: 256 thr = 16 nodes, W2^T staged in LDS. NEW: nodes
// processed in degree-sorted perm order (uniform degree within a block ->
// barrier couples equal-work lane groups); outputs scattered to original ids.
__global__ __launch_bounds__(256) void agg1_gemm2(const int* __restrict__ rowptr,
                                                  const int* __restrict__ srcidx,
                                                  const u16* __restrict__ hs,     // h1s [N][128] bf16
                                                  const float* __restrict__ dinv,
                                                  const float* __restrict__ bias, // b1
                                                  const u16* __restrict__ WT2,    // [64][128] bf16
                                                  const int* __restrict__ perm,
                                                  u16* __restrict__ h2s, int N) {
    constexpr int WPN = 16;   // lanes per node (128 feats / 8 per lane)
    constexpr int LDK = 136;
    __shared__ u16 sO[16 * LDK];
    __shared__ u16 sW[64 * LDK];

    const int t = threadIdx.x;
    const int node_l = t / WPN;         // 0..15
    const int fl = t % WPN;
    const int idx = blockIdx.x * 16 + node_l;
    const bool valid = idx < N;
    const int node = valid ? perm[idx] : 0;

    // stage W2^T [64][128]
    for (int i2 = t; i2 < 64 * 16; i2 += 256) {
        int n = i2 >> 4, c = i2 & 15;
        *((uint4*)&sW[n * LDK + c * 8]) = ((const uint4*)WT2)[i2];
    }

    // ---- phase 1: aggregation ----
    const uint4* h128 = (const uint4*)hs;
    float a[8];
#pragma unroll
    for (int j = 0; j < 8; j++) a[j] = 0.f;

    if (valid) {
        int start = rowptr[node], end = rowptr[node + 1];
        {
            uint4 v = h128[(size_t)node * WPN + fl];  // self loop
            a[0] = bflo(v.x); a[1] = bfhi(v.x); a[2] = bflo(v.y); a[3] = bfhi(v.y);
            a[4] = bflo(v.z); a[5] = bfhi(v.z); a[6] = bflo(v.w); a[7] = bfhi(v.w);
        }
        int nfull = (end - start) >> 3;
        int i = start;
        int r[8], r2[8];
        if (nfull > 0) {
#pragma unroll
            for (int j = 0; j < 8; j++) r[j] = srcidx[i + j];
        }
        for (int b = 0; b < nfull; b++) {
            uint4 u[8];
#pragma unroll
            for (int j = 0; j < 8; j++) u[j] = h128[(size_t)r[j] * WPN + fl];
            if (b + 1 < nfull) {
#pragma unroll
                for (int j = 0; j < 8; j++) r2[j] = srcidx[i + 8 + j];
            }
#pragma unroll
            for (int j = 0; j < 8; j++) {
                a[0] += bflo(u[j].x); a[1] += bfhi(u[j].x);
                a[2] += bflo(u[j].y); a[3] += bfhi(u[j].y);
                a[4] += bflo(u[j].z); a[5] += bfhi(u[j].z);
                a[6] += bflo(u[j].w); a[7] += bfhi(u[j].w);
            }
#pragma unroll
            for (int j = 0; j < 8; j++) r[j] = r2[j];
            i += 8;
        }
        if (i + 4 <= end) {
            int rr[4];
#pragma unroll
            for (int j = 0; j < 4; j++) rr[j] = srcidx[i + j];
            uint4 u[4];
#pragma unroll
            for (int j = 0; j < 4; j++) u[j] = h128[(size_t)rr[j] * WPN + fl];
#pragma unroll
            for (int j = 0; j < 4; j++) {
                a[0] += bflo(u[j].x); a[1] += bfhi(u[j].x);
                a[2] += bflo(u[j].y); a[3] += bfhi(u[j].y);
                a[4] += bflo(u[j].z); a[5] += bfhi(u[j].z);
                a[6] += bflo(u[j].w); a[7] += bfhi(u[j].w);
            }
            i += 4;
        }
        for (; i < end; ++i) {
            uint4 u = h128[(size_t)srcidx[i] * WPN + fl];
            a[0] += bflo(u.x); a[1] += bfhi(u.x);
            a[2] += bflo(u.y); a[3] += bfhi(u.y);
            a[4] += bflo(u.z); a[5] += bfhi(u.z);
            a[6] += bflo(u.w); a[7] += bfhi(u.w);
        }
    }

    float dv = valid ? dinv[node] : 0.f;
    float4 bv0 = ((const float4*)bias)[2 * fl];
    float4 bv1 = ((const float4*)bias)[2 * fl + 1];
    float o[8];
    o[0] = fmaxf(dv * a[0] + bv0.x, 0.f); o[1] = fmaxf(dv * a[1] + bv0.y, 0.f);
    o[2] = fmaxf(dv * a[2] + bv0.z, 0.f); o[3] = fmaxf(dv * a[3] + bv0.w, 0.f);
    o[4] = fmaxf(dv * a[4] + bv1.x, 0.f); o[5] = fmaxf(dv * a[5] + bv1.y, 0.f);
    o[6] = fmaxf(dv * a[6] + bv1.z, 0.f); o[7] = fmaxf(dv * a[7] + bv1.w, 0.f);
    uint4 w;
    w.x = (unsigned)f2bf(o[0]) | ((unsigned)f2bf(o[1]) << 16);
    w.y = (unsigned)f2bf(o[2]) | ((unsigned)f2bf(o[3]) << 16);
    w.z = (unsigned)f2bf(o[4]) | ((unsigned)f2bf(o[5]) << 16);
    w.w = (unsigned)f2bf(o[6]) | ((unsigned)f2bf(o[7]) << 16);
    *((uint4*)&sO[node_l * LDK + fl * 8]) = w;
    __syncthreads();

    // ---- phase 2: 16x64 GEMM vs W2 (wave wv -> feature tile wv*16) ----
    const int wv = t >> 6, lane = t & 63;
    const int m = lane & 15, q = lane >> 4;
    f32x4 acc = (f32x4){0.f, 0.f, 0.f, 0.f};
#pragma unroll
    for (int ks = 0; ks < 4; ks++) {
        const int k0 = ks * 32 + q * 8;
        bf16x8 af = *((const bf16x8*)&sO[m * LDK + k0]);
        bf16x8 bf = *((const bf16x8*)&sW[(wv * 16 + m) * LDK + k0]);
        acc = __builtin_amdgcn_mfma_f32_16x16x32_bf16(af, bf, acc, 0, 0, 0);
    }
#pragma unroll
    for (int r = 0; r < 4; r++) {
        int gidx = blockIdx.x * 16 + q * 4 + r;
        if (gidx < N) {
            int gnode = perm[gidx];
            float dvv = dinv[gnode];
            h2s[(size_t)gnode * 64 + wv * 16 + m] = f2bf(acc[r] * dvv);
        }
    }
}

// ---- aggregate+finalize (layer 2): out[c] = dinv[c]*(Σ h2s[r] + h2s[c]) + b2;
//      nodes processed in degree-sorted perm order ----
template <int NH, bool RELU, bool OUT_BF16>
__global__ __launch_bounds__(256) void aggregate(const int* __restrict__ rowptr,
                                                 const int* __restrict__ srcidx,
                                                 const u16* __restrict__ hs,
                                                 const float* __restrict__ dinv,
                                                 const float* __restrict__ bias,
                                                 const int* __restrict__ perm,
                                                 void* __restrict__ outv, int N) {
    constexpr int WPN = NH / 8;
    int tid = blockIdx.x * 256 + threadIdx.x;
    int idx = tid / WPN;
    int fl = tid % WPN;
    if (idx >= N) return;
    int node = perm[idx];

    const uint4* h128 = (const uint4*)hs;
    int start = rowptr[node], end = rowptr[node + 1];

    float a[8];
    {
        uint4 v = h128[(size_t)node * WPN + fl];
        a[0] = bflo(v.x); a[1] = bfhi(v.x); a[2] = bflo(v.y); a[3] = bfhi(v.y);
        a[4] = bflo(v.z); a[5] = bfhi(v.z); a[6] = bflo(v.w); a[7] = bfhi(v.w);
    }

    int nfull = (end - start) >> 3;
    int i = start;
    int r[8], r2[8];
    if (nfull > 0) {
#pragma unroll
        for (int j = 0; j < 8; j++) r[j] = srcidx[i + j];
    }
    for (int b = 0; b < nfull; b++) {
        uint4 u[8];
#pragma unroll
        for (int j = 0; j < 8; j++) u[j] = h128[(size_t)r[j] * WPN + fl];
        if (b + 1 < nfull) {
#pragma unroll
            for (int j = 0; j < 8; j++) r2[j] = srcidx[i + 8 + j];
        }
#pragma unroll
        for (int j = 0; j < 8; j++) {
            a[0] += bflo(u[j].x); a[1] += bfhi(u[j].x);
            a[2] += bflo(u[j].y); a[3] += bfhi(u[j].y);
            a[4] += bflo(u[j].z); a[5] += bfhi(u[j].z);
            a[6] += bflo(u[j].w); a[7] += bfhi(u[j].w);
        }
#pragma unroll
        for (int j = 0; j < 8; j++) r[j] = r2[j];
        i += 8;
    }
    if (i + 4 <= end) {
        int rr[4];
#pragma unroll
        for (int j = 0; j < 4; j++) rr[j] = srcidx[i + j];
        uint4 u[4];
#pragma unroll
        for (int j = 0; j < 4; j++) u[j] = h128[(size_t)rr[j] * WPN + fl];
#pragma unroll
        for (int j = 0; j < 4; j++) {
            a[0] += bflo(u[j].x); a[1] += bfhi(u[j].x);
            a[2] += bflo(u[j].y); a[3] += bfhi(u[j].y);
            a[4] += bflo(u[j].z); a[5] += bfhi(u[j].z);
            a[6] += bflo(u[j].w); a[7] += bfhi(u[j].w);
        }
        i += 4;
    }
    for (; i < end; ++i) {
        uint4 u = h128[(size_t)srcidx[i] * WPN + fl];
        a[0] += bflo(u.x); a[1] += bfhi(u.x);
        a[2] += bflo(u.y); a[3] += bfhi(u.y);
        a[4] += bflo(u.z); a[5] += bfhi(u.z);
        a[6] += bflo(u.w); a[7] += bfhi(u.w);
    }

    float dv = dinv[node];
    float4 bv0 = ((const float4*)bias)[2 * fl];
    float4 bv1 = ((const float4*)bias)[2 * fl + 1];
    float o[8];
    o[0] = dv * a[0] + bv0.x; o[1] = dv * a[1] + bv0.y;
    o[2] = dv * a[2] + bv0.z; o[3] = dv * a[3] + bv0.w;
    o[4] = dv * a[4] + bv1.x; o[5] = dv * a[5] + bv1.y;
    o[6] = dv * a[6] + bv1.z; o[7] = dv * a[7] + bv1.w;
    if (RELU) {
#pragma unroll
        for (int j = 0; j < 8; j++) o[j] = fmaxf(o[j], 0.f);
    }
    size_t obase = (size_t)node * WPN + fl;
    if (OUT_BF16) {
        uint4 w;
        w.x = (unsigned)f2bf(o[0]) | ((unsigned)f2bf(o[1]) << 16);
        w.y = (unsigned)f2bf(o[2]) | ((unsigned)f2bf(o[3]) << 16);
        w.z = (unsigned)f2bf(o[4]) | ((unsigned)f2bf(o[5]) << 16);
        w.w = (unsigned)f2bf(o[6]) | ((unsigned)f2bf(o[7]) << 16);
        ((uint4*)outv)[obase] = w;
    } else {
        ((float4*)outv)[2 * obase] = make_float4(o[0], o[1], o[2], o[3]);
        ((float4*)outv)[2 * obase + 1] = make_float4(o[4], o[5], o[6], o[7]);
    }
}

extern "C" void kernel_launch(void* const* d_in, const int* in_sizes, int n_in,
                              void* d_out, int out_size, void* d_ws, size_t ws_size,
                              hipStream_t stream) {
    const float* x  = (const float*)d_in[0];
    const int*   ei = (const int*)d_in[1];
    const float* W1 = (const float*)d_in[2];
    const float* b1 = (const float*)d_in[3];
    const float* W2 = (const float*)d_in[4];
    const float* b2 = (const float*)d_in[5];

    const int N = in_sizes[0] / 128;
    const int E = in_sizes[1] / 2;
    const int* rows = ei;
    const int* cols = ei + E;

    const int nbuckets = (N + BN - 1) / BN;          // 196 for N=100k (<=256)
    const int nblocksA = (E + CHUNK - 1) / CHUNK;    // 196 for E=1.6M (<=256)

    char* ws = (char*)d_ws;
    size_t off = 0;
    auto alloc = [&](size_t bytes) -> void* {
        void* p = ws + off;
        off = (off + bytes + 1023) & ~(size_t)1023;
        return p;
    };
    unsigned* hist       = (unsigned*)alloc((size_t)nbuckets * nblocksA * 4);
    unsigned* totals     = (unsigned*)alloc(256 * 4);
    unsigned* bucketbase = (unsigned*)alloc((size_t)(nbuckets + 1) * 4);
    unsigned* binned     = (unsigned*)alloc((size_t)E * 4);
    int*      rowptr     = (int*)alloc((size_t)(N + 1) * 4);
    float*    dinv       = (float*)alloc((size_t)N * 4);
    int*      srcidx     = (int*)alloc((size_t)E * 4);
    int*      perm       = (int*)alloc((size_t)N * 4);
    u16*      WT1        = (u16*)alloc((size_t)128 * 128 * 2);
    u16*      WT2        = (u16*)alloc((size_t)64 * 128 * 2);
    u16*      h1s        = (u16*)alloc((size_t)N * 128 * 2);
    u16*      h2s        = (u16*)alloc((size_t)N * 64 * 2);

    // CSR build (binned two-level counting sort) + fused weight prep
    hist_prep_kernel<<<nblocksA + 96, 256, 0, stream>>>(cols, hist, E, nbuckets, nblocksA,
                                                        W1, W2, WT1, WT2);
    scanA1_kernel<<<nbuckets, 256, 0, stream>>>(hist, totals, nblocksA, nbuckets);
    scanA2_kernel<<<1, 256, 0, stream>>>(totals, bucketbase, nbuckets);
    scatterA_kernel<<<nblocksA, 256, 0, stream>>>(rows, cols, hist, bucketbase, binned, E, nbuckets);
    binB_kernel<<<nbuckets, 256, 0, stream>>>(binned, bucketbase, rowptr, dinv, srcidx, perm,
                                              N, E, nbuckets);

    // layer 1 GEMM
    gemm_mfma<128, false><<<(N + 63) / 64, 256, 0, stream>>>(x, WT1, dinv, h1s, N);

    // fused: layer-1 aggregate + relu + layer-2 GEMM (degree-sorted node order)
    agg1_gemm2<<<(N + 15) / 16, 256, 0, stream>>>(rowptr, srcidx, h1s, dinv, b1, WT2, perm, h2s, N);

    // layer-2 aggregate + bias -> fp32 out (degree-sorted node order)
    aggregate<64, false, false><<<(N * 8 + 255) / 256, 256, 0, stream>>>(
        rowptr, srcidx, h2s, dinv, b2, perm, d_out, N);
}

// Round 5
// 261.320 us; speedup vs baseline: 1.0972x; 1.0894x over previous
//
#include <hip/hip_runtime.h>
#include <hip/hip_bf16.h>

typedef unsigned short u16;
typedef unsigned char u8;
typedef short bf16x8 __attribute__((ext_vector_type(8)));
typedef float f32x4 __attribute__((ext_vector_type(4)));

__device__ __forceinline__ float bflo(unsigned u) { return __uint_as_float(u << 16); }
__device__ __forceinline__ float bfhi(unsigned u) { return __uint_as_float(u & 0xffff0000u); }
__device__ __forceinline__ u16 f2bf(float f) {
    unsigned u = __float_as_uint(f);
    return (u16)((u + 0x7fffu + ((u >> 16) & 1u)) >> 16);  // RNE
}

#define CHUNK 2048     // edges per block in pass A (2048 -> 782 blocks: fills
                       // all 256 CUs with ~3 blocks each; 8192 left 60 CUs idle
                       // with exactly 1 block = no latency hiding)
#define BN 512         // nodes per bucket (bucket = c >> 9)

// binned entry packing: r in bits [0,23), (c & 511) in bits [23,32).
// Requires N <= 2^17 (N=100000) so r fits; bucket id recovered via LDS sideband.
#define PK_RMASK 0x7fffffu

// ---- pass A1: per-block bucket histogram (hist layout: [blk][bucket])
//      + fused W->bf16 transpose in trailing blocks ----
__global__ __launch_bounds__(256) void hist_prep_kernel(const int* __restrict__ cols,
                                                        unsigned* __restrict__ hist,
                                                        int E, int nbuckets, int nblocksA,
                                                        const float* __restrict__ W1,
                                                        const float* __restrict__ W2,
                                                        u16* __restrict__ WT1,
                                                        u16* __restrict__ WT2) {
    int blk = blockIdx.x;
    if (blk >= nblocksA) {
        int t = (blk - nblocksA) * 256 + threadIdx.x;
        if (t < 128 * 128) {
            int n = t >> 7, k = t & 127;
            WT1[n * 128 + k] = f2bf(W1[k * 128 + n]);
        } else if (t < 128 * 128 + 64 * 128) {
            int i = t - 128 * 128;
            int n = i >> 7, k = i & 127;
            WT2[n * 128 + k] = f2bf(W2[k * 64 + n]);
        }
        return;
    }
    __shared__ unsigned h[256];
    int t = threadIdx.x;
    h[t] = 0;
    __syncthreads();
    int base = blk * CHUNK;
#pragma unroll
    for (int j = 0; j < CHUNK / 256; j++) {
        int i = base + j * 256 + t;
        if (i < E) atomicAdd(&h[((unsigned)cols[i]) >> 9], 1u);
    }
    __syncthreads();
    if (t < nbuckets) hist[blk * nbuckets + t] = h[t];
}

// ---- pass A2a: per-bucket prefix over blocks (one WG per bucket).
//      4 entries per thread -> supports nblocksA <= 1024. ----
__global__ __launch_bounds__(256) void scanA1_kernel(unsigned* __restrict__ hist,
                                                     unsigned* __restrict__ totals,
                                                     int nblocksA, int nbuckets) {
    __shared__ unsigned s[256];
    int t = threadIdx.x, b = blockIdx.x;
    unsigned v[4];
    unsigned sum = 0;
#pragma unroll
    for (int k = 0; k < 4; k++) {
        int blk = t * 4 + k;
        v[k] = (blk < nblocksA) ? hist[(size_t)blk * nbuckets + b] : 0u;
        sum += v[k];
    }
    s[t] = sum;
    __syncthreads();
    unsigned val = sum;
    for (int off = 1; off < 256; off <<= 1) {
        unsigned x = (t >= off) ? s[t - off] : 0u;
        __syncthreads();
        s[t] += x;
        __syncthreads();
    }
    unsigned ex = s[t] - val;   // exclusive over 4-element groups
#pragma unroll
    for (int k = 0; k < 4; k++) {
        int blk = t * 4 + k;
        if (blk < nblocksA) hist[(size_t)blk * nbuckets + b] = ex;
        ex += v[k];
    }
    if (t == 255) totals[b] = s[255];
}

// ---- pass A2b: bucket bases (single WG) ----
__global__ __launch_bounds__(256) void scanA2_kernel(const unsigned* __restrict__ totals,
                                                     unsigned* __restrict__ bucketbase,
                                                     int nbuckets) {
    __shared__ unsigned s[256];
    int t = threadIdx.x;
    unsigned val = (t < nbuckets) ? totals[t] : 0u;
    s[t] = val;
    __syncthreads();
    for (int off = 1; off < 256; off <<= 1) {
        unsigned v = (t >= off) ? s[t - off] : 0u;
        __syncthreads();
        s[t] += v;
        __syncthreads();
    }
    unsigned ex = s[t] - val;
    if (t < nbuckets) bucketbase[t] = ex;
    if (t == nbuckets - 1) bucketbase[nbuckets] = ex + val;  // == E
}

// ---- pass A3: LDS-staged scatter -> coalesced bucket-group writes ----
// binned entries are packed u32 (halved traffic vs uint2); bucket id for the
// write phase is kept in a u8 sideband (nbuckets <= 256). LDS ~13 KB.
__global__ __launch_bounds__(256) void scatterA_kernel(const int* __restrict__ rows,
                                                       const int* __restrict__ cols,
                                                       const unsigned* __restrict__ hist,
                                                       const unsigned* __restrict__ bucketbase,
                                                       unsigned* __restrict__ binned,
                                                       int E, int nbuckets) {
    __shared__ unsigned sp[CHUNK];     // 8 KB staging (packed)
    __shared__ u8 spg[CHUNK];          // 2 KB bucket ids
    __shared__ unsigned lstart[256];   // LDS group starts
    __shared__ unsigned lcur[256];     // cursors
    __shared__ unsigned gbase[256];    // global base per bucket for this block
    int t = threadIdx.x, blk = blockIdx.x;
    int base = blk * CHUNK;
    int cnt = min(CHUNK, E - base);

    lcur[t] = 0;
    __syncthreads();
    for (int i = t; i < cnt; i += 256)
        atomicAdd(&lcur[((unsigned)cols[base + i]) >> 9], 1u);
    __syncthreads();
    unsigned val = lcur[t];
    lstart[t] = val;
    __syncthreads();
    for (int off = 1; off < 256; off <<= 1) {
        unsigned v = (t >= off) ? lstart[t - off] : 0u;
        __syncthreads();
        lstart[t] += v;
        __syncthreads();
    }
    unsigned ex = lstart[t] - val;
    __syncthreads();
    lstart[t] = ex;
    lcur[t] = ex;
    if (t < nbuckets) gbase[t] = bucketbase[t] + hist[(size_t)blk * nbuckets + t];
    __syncthreads();
    for (int i = t; i < cnt; i += 256) {
        unsigned c = (unsigned)cols[base + i];
        unsigned r = (unsigned)rows[base + i];
        unsigned g = c >> 9;
        unsigned pos = atomicAdd(&lcur[g], 1u);
        sp[pos] = r | ((c & 511u) << 23);
        spg[pos] = (u8)g;
    }
    __syncthreads();
    for (int i = t; i < cnt; i += 256) {
        unsigned pk = sp[i];
        unsigned g = spg[i];
        binned[gbase[g] + (unsigned)i - lstart[g]] = pk;
    }
}

// ---- pass B: per bucket — local count/scan -> rowptr, dinv, srcidx ----
__global__ __launch_bounds__(256) void binB_kernel(const unsigned* __restrict__ binned,
                                                   const unsigned* __restrict__ bucketbase,
                                                   int* __restrict__ rowptr,
                                                   float* __restrict__ dinv,
                                                   int* __restrict__ srcidx,
                                                   int N, int E, int nbuckets) {
    __shared__ unsigned cnt[BN + 1];
    __shared__ unsigned sc[BN + 1];
    __shared__ unsigned ps[256];
    int t = threadIdx.x, b = blockIdx.x;
    int lo = b << 9;
    int nn = min(BN, N - lo);
    unsigned s = bucketbase[b], e = bucketbase[b + 1];

    cnt[t] = 0;
    cnt[t + 256] = 0;
    if (t == 0) cnt[BN] = 0;
    __syncthreads();
    for (unsigned i = s + t; i < e; i += 256)
        atomicAdd(&cnt[binned[i] >> 23], 1u);
    __syncthreads();

    unsigned a0 = cnt[2 * t], a1 = cnt[2 * t + 1];
    ps[t] = a0 + a1;
    __syncthreads();
    unsigned val = ps[t];
    for (int off = 1; off < 256; off <<= 1) {
        unsigned v = (t >= off) ? ps[t - off] : 0u;
        __syncthreads();
        ps[t] += v;
        __syncthreads();
    }
    unsigned ex = ps[t] - val;
    sc[2 * t] = ex;
    sc[2 * t + 1] = ex + a0;
    if (t == 255) sc[BN] = ex + val;
    __syncthreads();

    for (int n = t; n < nn; n += 256) {
        unsigned rp = s + sc[n];
        rowptr[lo + n] = (int)rp;
        dinv[lo + n] = rsqrtf((float)(sc[n + 1] - sc[n]) + 1.0f);
        cnt[n] = rp;
    }
    if (b == nbuckets - 1 && t == 0) rowptr[N] = E;
    __syncthreads();

    for (unsigned i = s + t; i < e; i += 256) {
        unsigned pk = binned[i];
        unsigned slot = atomicAdd(&cnt[pk >> 23], 1u);
        srcidx[slot] = (int)(pk & PK_RMASK);
    }
}

// ---- MFMA bf16 GEMM: OutH[i,:] = bf16((X[i,:] @ W) * dinv[i]) ----
template <int NOUT, bool IN_BF16>
__global__ __launch_bounds__(256) void gemm_mfma(const void* __restrict__ Xv,
                                                 const u16* __restrict__ WT,  // [NOUT][128] bf16
                                                 const float* __restrict__ dinv,
                                                 u16* __restrict__ OutH, int nrows) {
    constexpr int LDK = 136;
    __shared__ u16 sX[64 * LDK];
    __shared__ u16 sW[NOUT * LDK];

    const int t = threadIdx.x;
    const int wv = t >> 6, lane = t & 63;
    const int m = lane & 15, q = lane >> 4;
    const int row0 = blockIdx.x * 64;

    for (int idx = t; idx < NOUT * 16; idx += 256) {
        int n = idx >> 4, c = idx & 15;
        *((uint4*)&sW[n * LDK + c * 8]) = ((const uint4*)WT)[idx];
    }
    if (IN_BF16) {
        const u16* X = (const u16*)Xv;
        for (int idx = t; idx < 64 * 16; idx += 256) {
            int r = idx >> 4, c = idx & 15;
            int gr = row0 + r;
            uint4 v = make_uint4(0u, 0u, 0u, 0u);
            if (gr < nrows) v = ((const uint4*)X)[(size_t)gr * 16 + c];
            *((uint4*)&sX[r * LDK + c * 8]) = v;
        }
    } else {
        const float* X = (const float*)Xv;
        for (int idx = t; idx < 64 * 32; idx += 256) {
            int r = idx >> 5, c = idx & 31;
            int gr = row0 + r;
            float4 v = make_float4(0.f, 0.f, 0.f, 0.f);
            if (gr < nrows) v = ((const float4*)X)[(size_t)gr * 32 + c];
            uint2 o;
            o.x = (unsigned)f2bf(v.x) | ((unsigned)f2bf(v.y) << 16);
            o.y = (unsigned)f2bf(v.z) | ((unsigned)f2bf(v.w) << 16);
            *((uint2*)&sX[r * LDK + c * 4]) = o;
        }
    }
    __syncthreads();

    f32x4 acc[NOUT / 16];
#pragma unroll
    for (int i = 0; i < NOUT / 16; i++) acc[i] = (f32x4){0.f, 0.f, 0.f, 0.f};

#pragma unroll
    for (int ks = 0; ks < 4; ks++) {
        const int k0 = ks * 32 + q * 8;
        bf16x8 a = *((const bf16x8*)&sX[(wv * 16 + m) * LDK + k0]);
#pragma unroll
        for (int nt = 0; nt < NOUT / 16; nt++) {
            bf16x8 b = *((const bf16x8*)&sW[(nt * 16 + m) * LDK + k0]);
            acc[nt] = __builtin_amdgcn_mfma_f32_16x16x32_bf16(a, b, acc[nt], 0, 0, 0);
        }
    }

#pragma unroll
    for (int r = 0; r < 4; r++) {
        int gi = row0 + wv * 16 + q * 4 + r;
        if (gi < nrows) {
            float dv = dinv[gi];
#pragma unroll
            for (int nt = 0; nt < NOUT / 16; nt++) {
                OutH[(size_t)gi * NOUT + nt * 16 + m] = f2bf(acc[nt][r] * dv);
            }
        }
    }
}

// ---- fused layer-1 aggregate + relu + layer-2 GEMM ----
// Round-0 measured-optimal shape: 256 thr = 16 nodes/blk, W2^T staged in LDS,
// natural node order. Structural variants tested and all slower:
// 512-thr (72.8), no-W2-stage+100%occ (70.7), degree-sorted perm (77.4) vs 67.8.
// The gather runs at the L2-miss-path structural rate (~2.8 TB/s FETCH).
__global__ __launch_bounds__(256) void agg1_gemm2(const int* __restrict__ rowptr,
                                                  const int* __restrict__ srcidx,
                                                  const u16* __restrict__ hs,     // h1s [N][128] bf16
                                                  const float* __restrict__ dinv,
                                                  const float* __restrict__ bias, // b1
                                                  const u16* __restrict__ WT2,    // [64][128] bf16
                                                  u16* __restrict__ h2s, int N) {
    constexpr int WPN = 16;   // lanes per node (128 feats / 8 per lane)
    constexpr int LDK = 136;
    __shared__ u16 sO[16 * LDK];
    __shared__ u16 sW[64 * LDK];

    const int t = threadIdx.x;
    const int node_l = t / WPN;         // 0..15
    const int fl = t % WPN;
    const int node = blockIdx.x * 16 + node_l;
    const bool valid = node < N;

    // stage W2^T [64][128]
    for (int idx = t; idx < 64 * 16; idx += 256) {
        int n = idx >> 4, c = idx & 15;
        *((uint4*)&sW[n * LDK + c * 8]) = ((const uint4*)WT2)[idx];
    }

    // ---- phase 1: aggregation ----
    const uint4* h128 = (const uint4*)hs;
    float a[8];
#pragma unroll
    for (int j = 0; j < 8; j++) a[j] = 0.f;

    if (valid) {
        int start = rowptr[node], end = rowptr[node + 1];
        {
            uint4 v = h128[(size_t)node * WPN + fl];  // self loop
            a[0] = bflo(v.x); a[1] = bfhi(v.x); a[2] = bflo(v.y); a[3] = bfhi(v.y);
            a[4] = bflo(v.z); a[5] = bfhi(v.z); a[6] = bflo(v.w); a[7] = bfhi(v.w);
        }
        int nfull = (end - start) >> 3;
        int i = start;
        int r[8], r2[8];
        if (nfull > 0) {
#pragma unroll
            for (int j = 0; j < 8; j++) r[j] = srcidx[i + j];
        }
        for (int b = 0; b < nfull; b++) {
            uint4 u[8];
#pragma unroll
            for (int j = 0; j < 8; j++) u[j] = h128[(size_t)r[j] * WPN + fl];
            if (b + 1 < nfull) {
#pragma unroll
                for (int j = 0; j < 8; j++) r2[j] = srcidx[i + 8 + j];
            }
#pragma unroll
            for (int j = 0; j < 8; j++) {
                a[0] += bflo(u[j].x); a[1] += bfhi(u[j].x);
                a[2] += bflo(u[j].y); a[3] += bfhi(u[j].y);
                a[4] += bflo(u[j].z); a[5] += bfhi(u[j].z);
                a[6] += bflo(u[j].w); a[7] += bfhi(u[j].w);
            }
#pragma unroll
            for (int j = 0; j < 8; j++) r[j] = r2[j];
            i += 8;
        }
        if (i + 4 <= end) {
            int rr[4];
#pragma unroll
            for (int j = 0; j < 4; j++) rr[j] = srcidx[i + j];
            uint4 u[4];
#pragma unroll
            for (int j = 0; j < 4; j++) u[j] = h128[(size_t)rr[j] * WPN + fl];
#pragma unroll
            for (int j = 0; j < 4; j++) {
                a[0] += bflo(u[j].x); a[1] += bfhi(u[j].x);
                a[2] += bflo(u[j].y); a[3] += bfhi(u[j].y);
                a[4] += bflo(u[j].z); a[5] += bfhi(u[j].z);
                a[6] += bflo(u[j].w); a[7] += bfhi(u[j].w);
            }
            i += 4;
        }
        for (; i < end; ++i) {
            uint4 u = h128[(size_t)srcidx[i] * WPN + fl];
            a[0] += bflo(u.x); a[1] += bfhi(u.x);
            a[2] += bflo(u.y); a[3] += bfhi(u.y);
            a[4] += bflo(u.z); a[5] += bfhi(u.z);
            a[6] += bflo(u.w); a[7] += bfhi(u.w);
        }
    }

    float dv = valid ? dinv[node] : 0.f;
    float4 bv0 = ((const float4*)bias)[2 * fl];
    float4 bv1 = ((const float4*)bias)[2 * fl + 1];
    float o[8];
    o[0] = fmaxf(dv * a[0] + bv0.x, 0.f); o[1] = fmaxf(dv * a[1] + bv0.y, 0.f);
    o[2] = fmaxf(dv * a[2] + bv0.z, 0.f); o[3] = fmaxf(dv * a[3] + bv0.w, 0.f);
    o[4] = fmaxf(dv * a[4] + bv1.x, 0.f); o[5] = fmaxf(dv * a[5] + bv1.y, 0.f);
    o[6] = fmaxf(dv * a[6] + bv1.z, 0.f); o[7] = fmaxf(dv * a[7] + bv1.w, 0.f);
    uint4 w;
    w.x = (unsigned)f2bf(o[0]) | ((unsigned)f2bf(o[1]) << 16);
    w.y = (unsigned)f2bf(o[2]) | ((unsigned)f2bf(o[3]) << 16);
    w.z = (unsigned)f2bf(o[4]) | ((unsigned)f2bf(o[5]) << 16);
    w.w = (unsigned)f2bf(o[6]) | ((unsigned)f2bf(o[7]) << 16);
    *((uint4*)&sO[node_l * LDK + fl * 8]) = w;
    __syncthreads();

    // ---- phase 2: 16x64 GEMM vs W2 (wave wv -> feature tile wv*16) ----
    const int wv = t >> 6, lane = t & 63;
    const int m = lane & 15, q = lane >> 4;
    f32x4 acc = (f32x4){0.f, 0.f, 0.f, 0.f};
#pragma unroll
    for (int ks = 0; ks < 4; ks++) {
        const int k0 = ks * 32 + q * 8;
        bf16x8 af = *((const bf16x8*)&sO[m * LDK + k0]);
        bf16x8 bf = *((const bf16x8*)&sW[(wv * 16 + m) * LDK + k0]);
        acc = __builtin_amdgcn_mfma_f32_16x16x32_bf16(af, bf, acc, 0, 0, 0);
    }
#pragma unroll
    for (int r = 0; r < 4; r++) {
        int gi = blockIdx.x * 16 + q * 4 + r;
        if (gi < N) {
            float dvv = dinv[gi];
            h2s[(size_t)gi * 64 + wv * 16 + m] = f2bf(acc[r] * dvv);
        }
    }
}

// ---- aggregate+finalize (layer 2): out[c] = dinv[c]*(Σ h2s[r] + h2s[c]) + b2 ----
template <int NH, bool RELU, bool OUT_BF16>
__global__ __launch_bounds__(256) void aggregate(const int* __restrict__ rowptr,
                                                 const int* __restrict__ srcidx,
                                                 const u16* __restrict__ hs,
                                                 const float* __restrict__ dinv,
                                                 const float* __restrict__ bias,
                                                 void* __restrict__ outv, int N) {
    constexpr int WPN = NH / 8;
    int tid = blockIdx.x * 256 + threadIdx.x;
    int node = tid / WPN;
    int fl = tid % WPN;
    if (node >= N) return;

    const uint4* h128 = (const uint4*)hs;
    int start = rowptr[node], end = rowptr[node + 1];

    float a[8];
    {
        uint4 v = h128[(size_t)node * WPN + fl];
        a[0] = bflo(v.x); a[1] = bfhi(v.x); a[2] = bflo(v.y); a[3] = bfhi(v.y);
        a[4] = bflo(v.z); a[5] = bfhi(v.z); a[6] = bflo(v.w); a[7] = bfhi(v.w);
    }

    int nfull = (end - start) >> 3;
    int i = start;
    int r[8], r2[8];
    if (nfull > 0) {
#pragma unroll
        for (int j = 0; j < 8; j++) r[j] = srcidx[i + j];
    }
    for (int b = 0; b < nfull; b++) {
        uint4 u[8];
#pragma unroll
        for (int j = 0; j < 8; j++) u[j] = h128[(size_t)r[j] * WPN + fl];
        if (b + 1 < nfull) {
#pragma unroll
            for (int j = 0; j < 8; j++) r2[j] = srcidx[i + 8 + j];
        }
#pragma unroll
        for (int j = 0; j < 8; j++) {
            a[0] += bflo(u[j].x); a[1] += bfhi(u[j].x);
            a[2] += bflo(u[j].y); a[3] += bfhi(u[j].y);
            a[4] += bflo(u[j].z); a[5] += bfhi(u[j].z);
            a[6] += bflo(u[j].w); a[7] += bfhi(u[j].w);
        }
#pragma unroll
        for (int j = 0; j < 8; j++) r[j] = r2[j];
        i += 8;
    }
    if (i + 4 <= end) {
        int rr[4];
#pragma unroll
        for (int j = 0; j < 4; j++) rr[j] = srcidx[i + j];
        uint4 u[4];
#pragma unroll
        for (int j = 0; j < 4; j++) u[j] = h128[(size_t)rr[j] * WPN + fl];
#pragma unroll
        for (int j = 0; j < 4; j++) {
            a[0] += bflo(u[j].x); a[1] += bfhi(u[j].x);
            a[2] += bflo(u[j].y); a[3] += bfhi(u[j].y);
            a[4] += bflo(u[j].z); a[5] += bfhi(u[j].z);
            a[6] += bflo(u[j].w); a[7] += bfhi(u[j].w);
        }
        i += 4;
    }
    for (; i < end; ++i) {
        uint4 u = h128[(size_t)srcidx[i] * WPN + fl];
        a[0] += bflo(u.x); a[1] += bfhi(u.x);
        a[2] += bflo(u.y); a[3] += bfhi(u.y);
        a[4] += bflo(u.z); a[5] += bfhi(u.z);
        a[6] += bflo(u.w); a[7] += bfhi(u.w);
    }

    float dv = dinv[node];
    float4 bv0 = ((const float4*)bias)[2 * fl];
    float4 bv1 = ((const float4*)bias)[2 * fl + 1];
    float o[8];
    o[0] = dv * a[0] + bv0.x; o[1] = dv * a[1] + bv0.y;
    o[2] = dv * a[2] + bv0.z; o[3] = dv * a[3] + bv0.w;
    o[4] = dv * a[4] + bv1.x; o[5] = dv * a[5] + bv1.y;
    o[6] = dv * a[6] + bv1.z; o[7] = dv * a[7] + bv1.w;
    if (RELU) {
#pragma unroll
        for (int j = 0; j < 8; j++) o[j] = fmaxf(o[j], 0.f);
    }
    if (OUT_BF16) {
        uint4 w;
        w.x = (unsigned)f2bf(o[0]) | ((unsigned)f2bf(o[1]) << 16);
        w.y = (unsigned)f2bf(o[2]) | ((unsigned)f2bf(o[3]) << 16);
        w.z = (unsigned)f2bf(o[4]) | ((unsigned)f2bf(o[5]) << 16);
        w.w = (unsigned)f2bf(o[6]) | ((unsigned)f2bf(o[7]) << 16);
        ((uint4*)outv)[tid] = w;
    } else {
        ((float4*)outv)[2 * tid] = make_float4(o[0], o[1], o[2], o[3]);
        ((float4*)outv)[2 * tid + 1] = make_float4(o[4], o[5], o[6], o[7]);
    }
}

extern "C" void kernel_launch(void* const* d_in, const int* in_sizes, int n_in,
                              void* d_out, int out_size, void* d_ws, size_t ws_size,
                              hipStream_t stream) {
    const float* x  = (const float*)d_in[0];
    const int*   ei = (const int*)d_in[1];
    const float* W1 = (const float*)d_in[2];
    const float* b1 = (const float*)d_in[3];
    const float* W2 = (const float*)d_in[4];
    const float* b2 = (const float*)d_in[5];

    const int N = in_sizes[0] / 128;
    const int E = in_sizes[1] / 2;
    const int* rows = ei;
    const int* cols = ei + E;

    const int nbuckets = (N + BN - 1) / BN;          // 196 for N=100k (<=256)
    const int nblocksA = (E + CHUNK - 1) / CHUNK;    // 782 for E=1.6M (<=1024)

    char* ws = (char*)d_ws;
    size_t off = 0;
    auto alloc = [&](size_t bytes) -> void* {
        void* p = ws + off;
        off = (off + bytes + 1023) & ~(size_t)1023;
        return p;
    };
    unsigned* hist       = (unsigned*)alloc((size_t)nbuckets * nblocksA * 4);
    unsigned* totals     = (unsigned*)alloc(256 * 4);
    unsigned* bucketbase = (unsigned*)alloc((size_t)(nbuckets + 1) * 4);
    unsigned* binned     = (unsigned*)alloc((size_t)E * 4);
    int*      rowptr     = (int*)alloc((size_t)(N + 1) * 4);
    float*    dinv       = (float*)alloc((size_t)N * 4);
    int*      srcidx     = (int*)alloc((size_t)E * 4);
    u16*      WT1        = (u16*)alloc((size_t)128 * 128 * 2);
    u16*      WT2        = (u16*)alloc((size_t)64 * 128 * 2);
    u16*      h1s        = (u16*)alloc((size_t)N * 128 * 2);
    u16*      h2s        = (u16*)alloc((size_t)N * 64 * 2);

    // CSR build (binned two-level counting sort) + fused weight prep
    hist_prep_kernel<<<nblocksA + 96, 256, 0, stream>>>(cols, hist, E, nbuckets, nblocksA,
                                                        W1, W2, WT1, WT2);
    scanA1_kernel<<<nbuckets, 256, 0, stream>>>(hist, totals, nblocksA, nbuckets);
    scanA2_kernel<<<1, 256, 0, stream>>>(totals, bucketbase, nbuckets);
    scatterA_kernel<<<nblocksA, 256, 0, stream>>>(rows, cols, hist, bucketbase, binned, E, nbuckets);
    binB_kernel<<<nbuckets, 256, 0, stream>>>(binned, bucketbase, rowptr, dinv, srcidx, N, E, nbuckets);

    // layer 1 GEMM
    gemm_mfma<128, false><<<(N + 63) / 64, 256, 0, stream>>>(x, WT1, dinv, h1s, N);

    // fused: layer-1 aggregate + relu + layer-2 GEMM
    agg1_gemm2<<<(N + 15) / 16, 256, 0, stream>>>(rowptr, srcidx, h1s, dinv, b1, WT2, h2s, N);

    // layer-2 aggregate + bias -> fp32 out
    aggregate<64, false, false><<<(N * 8 + 255) / 256, 256, 0, stream>>>(
        rowptr, srcidx, h2s, dinv, b2, d_out, N);
}